// Round 8
// baseline (160.381 us; speedup 1.0000x reference)
//
#include <hip/hip_runtime.h>
#include <math.h>

#define Bsz 2048
#define Lsz 1024
#define SW  8   // waves (batches) per scan block

// ws layout (float offsets)
#define OFF_GS  0        // column-scaled Gram: Gs[v][j] = c_j * G[v][j]   64x64
#define OFF_PG  4096     // g_v * (h_v @ (read_w@out_w))  64x64
#define OFF_H   8192     // h table staging (prep1 -> prep2)  64x64
#define OFF_WC  12288    // read_w @ out_w  64x64
#define OFF_GV  16384    // g per token
#define OFF_CI  16448    // denom/g per token (1/c)
#define OFF_C   16512    // g/denom per token (c)
#define OFF_BC  16576    // read_b@out_w + out_b
// total 16640 floats = 66.6 KB

typedef float v32f __attribute__((ext_vector_type(32)));

__device__ __forceinline__ float __rlf(float v, int i) {
    return __int_as_float(__builtin_amdgcn_readlane(__float_as_int(v), i));
}

// ---------------- prep1: per-token h/g/c (blocks 0..63), Wc rows (64..127), bc (128)
__global__ __launch_bounds__(128) void prep1_kernel(
    const float* __restrict__ embed_W, const float* __restrict__ ff_w1, const float* __restrict__ ff_b1,
    const float* __restrict__ ff_w2, const float* __restrict__ ff_b2, const float* __restrict__ ln_g,
    const float* __restrict__ ln_b, const float* __restrict__ gate_w1, const float* __restrict__ gate_b1,
    const float* __restrict__ gate_w2, const float* __restrict__ gate_b2, const float* __restrict__ read_w,
    const float* __restrict__ read_b, const float* __restrict__ out_w, const float* __restrict__ out_b,
    float* __restrict__ ws)
{
    const int tid = threadIdx.x;
    const int blk = blockIdx.x;
    if (blk < 64) {
        const int v = blk;
        __shared__ float z[128];
        __shared__ float hsh[64];
        const float* Ev = embed_W + (v << 6);
        float a = ff_b1[tid];
        #pragma unroll
        for (int i = 0; i < 64; ++i) a = fmaf(Ev[i], ff_w1[i * 128 + tid], a);
        z[tid] = fmaxf(a, 0.0f);
        __syncthreads();
        if (tid < 64) {   // wave 0 only
            float x = Ev[tid] + ff_b2[tid];
            #pragma unroll
            for (int j = 0; j < 128; ++j) x = fmaf(z[j], ff_w2[j * 64 + tid], x);
            float mu = x;
            #pragma unroll
            for (int off = 32; off > 0; off >>= 1) mu += __shfl_xor(mu, off);
            mu *= (1.0f / 64.0f);
            const float dd = x - mu;
            float var = dd * dd;
            #pragma unroll
            for (int off = 32; off > 0; off >>= 1) var += __shfl_xor(var, off);
            var *= (1.0f / 64.0f);
            const float rstd = rsqrtf(var + 1e-5f);
            const float hv = fmaf(dd * rstd, ln_g[tid], ln_b[tid]);
            hsh[tid] = hv;
            ws[OFF_H + (v << 6) + tid] = hv;
            float dn = hv * hv;
            #pragma unroll
            for (int off = 32; off > 0; off >>= 1) dn += __shfl_xor(dn, off);
            dn += 1e-6f;
            float a2 = 0.0f;
            if (tid < 16) {
                float um = gate_b1[tid];
                #pragma unroll
                for (int i = 0; i < 64; ++i) um = fmaf(hsh[i], gate_w1[i * 16 + tid], um);
                a2 = fmaxf(um, 0.0f) * gate_w2[tid];
            }
            #pragma unroll
            for (int off = 8; off > 0; off >>= 1) a2 += __shfl_xor(a2, off);
            if (tid == 0) {
                a2 += gate_b2[0];
                const float g = 1.0f / (1.0f + expf(-a2));
                ws[OFF_GV + v] = g;
                ws[OFF_C  + v] = g / dn;
                ws[OFF_CI + v] = dn / g;
            }
        }
    } else if (blk < 128) {
        const int j = blk - 64;
        if (tid < 64) {
            float a = 0.0f;
            #pragma unroll
            for (int m = 0; m < 64; ++m) a = fmaf(read_w[(j << 6) + m], out_w[(m << 6) + tid], a);
            ws[OFF_WC + (j << 6) + tid] = a;
        }
    } else {
        if (tid < 64) {
            float a = out_b[tid];
            #pragma unroll
            for (int jj = 0; jj < 64; ++jj) a = fmaf(read_b[jj], out_w[(jj << 6) + tid], a);
            ws[OFF_BC + tid] = a;
        }
    }
}

// ---------------- prep2: 32 blocks x 256 threads; wave-row r = blk*4+wave:
// r<64 -> Gs row r (column-scaled Gram); else Pg row r-64 (g folded).
__global__ __launch_bounds__(256) void prep2_kernel(float* __restrict__ ws)
{
    const int tid = threadIdx.x;
    const int blk = blockIdx.x;
    __shared__ float tT[65 * 64];   // tT[j*65+w] = h[w][j] (padded)
    for (int idx = tid; idx < 4096; idx += 256) {
        const int w = idx >> 6, j = idx & 63;
        tT[j * 65 + w] = ws[OFF_H + idx];
    }
    __syncthreads();
    const int wave = tid >> 6, lane = tid & 63;
    const int r = blk * 4 + wave;
    if (r < 64) {
        const int v = r;
        float a = 0.0f;
        #pragma unroll
        for (int j = 0; j < 64; ++j) a = fmaf(tT[j * 65 + v], tT[j * 65 + lane], a);
        ws[OFF_GS + (v << 6) + lane] = ws[OFF_C + lane] * a;   // scale by COLUMN c
    } else {
        const int v = r - 64;
        const float gv = ws[OFF_GV + v];
        float a = 0.0f;
        #pragma unroll
        for (int j = 0; j < 64; ++j)
            a = fmaf(tT[j * 65 + v], ws[OFF_WC + (j << 6) + lane], a);
        ws[OFF_PG + (v << 6) + lane] = gv * a;
    }
}

// ---------------- scan: one wave per batch; Gram table register-resident
// (2 x 32-wide vectors, indexed via uniform dynamic subscript -> v_movrels).
// No LDS and no memory ops in the main loop.
__global__ __launch_bounds__(SW * 64) void scan_kernel(const int* __restrict__ seq,
                                                       const float* __restrict__ ws,
                                                       float* __restrict__ out)
{
    __shared__ float ldsPg[4096];

    const int tid  = threadIdx.x;
    const int wave = tid >> 6;
    const int lane = tid & 63;
    const int b    = blockIdx.x * SW + wave;

    // token loads first
    const int4* ts = (const int4*)(seq + (size_t)b * Lsz);
    const int4 q0 = ts[lane], q1 = ts[64 + lane], q2 = ts[128 + lane], q3 = ts[192 + lane];

    // stage Pg to LDS (epilogue only)
    {
        const float4* s2 = (const float4*)(ws + OFF_PG);
        float4* d2 = (float4*)ldsPg;
        for (int i = tid; i < 1024; i += SW * 64) d2[i] = s2[i];
    }

    // register-resident scaled-Gram row for this lane: Gs[lane][0..63]
    const v32f lo = *(const v32f*)(ws + OFF_GS + (lane << 6));
    const v32f hi = *(const v32f*)(ws + OFF_GS + (lane << 6) + 32);
    const float civ = ws[OFF_CI + lane];
    const float bc  = ws[OFF_BC + lane];

    // pack tokens 4-per-int: byte k of lane l of tvp = token 4*(64p+l)+k
    int tv0 = q0.x | (q0.y << 8) | (q0.z << 16) | (q0.w << 24);
    int tv1 = q1.x | (q1.y << 8) | (q1.z << 16) | (q1.w << 24);
    int tv2 = q2.x | (q2.y << 8) | (q2.z << 16) | (q2.w << 24);
    int tv3 = q3.x | (q3.y << 8) | (q3.z << 16) | (q3.w << 24);

    const int tokL = (__builtin_amdgcn_readlane(tv3, 63) >> 24) & 0xFF;   // query token

    // D_v = G[v][tokL] = Gs[v][tokL] / c_tokL
    float D;
    {
        const int t5 = tokL & 31;
        const float a = lo[t5], h2 = hi[t5];
        const float gs = (tokL & 32) ? h2 : a;
        D = gs * __rlf(civ, tokL);
    }
    float u = 0.0f;

    auto DO_STEP = [&](int tok) {
        const int t5 = tok & 31;
        const float a  = lo[t5];            // v_movrels (uniform index)
        const float h2 = hi[t5];            // v_movrels
        const float gc = (tok & 32) ? h2 : a;
        const float d  = __rlf(D, tok);     // critical chain
        u += (lane == tok) ? d : 0.0f;      // off-chain
        D = fmaf(-d, gc, D);                // critical chain
    };

    // steps t = 1022..0 (t=1023 is the query, skipped).
    // word w = 4 tokens (low byte first); word uu of tvp = tokens 4*(64p+uu)+{0..3}
    {   // peeled word 255: steps 1022,1021,1020
        const int wv = __builtin_amdgcn_readlane(tv3, 63);
        DO_STEP((wv >> 16) & 0xFF);
        DO_STEP((wv >>  8) & 0xFF);
        DO_STEP( wv        & 0xFF);
    }
    #pragma unroll
    for (int p = 3; p >= 0; --p) {
        const int tvp = (p == 3) ? tv3 : (p == 2) ? tv2 : (p == 1) ? tv1 : tv0;
        const int ustart = (p == 3) ? 62 : 63;
        for (int uu = ustart; uu >= 0; --uu) {
            const int wv = __builtin_amdgcn_readlane(tvp, uu);
            DO_STEP((wv >> 24) & 0xFF);
            DO_STEP((wv >> 16) & 0xFF);
            DO_STEP((wv >>  8) & 0xFF);
            DO_STEP( wv        & 0xFF);
        }
    }

    __syncthreads();   // ldsPg writes (pre-loop) visible

    // epilogue: logits = u @ Pg + bc (g pre-folded into Pg)
    float acc = bc;
    #pragma unroll 16
    for (int v = 0; v < 64; ++v)
        acc = fmaf(__rlf(u, v), ldsPg[(v << 6) + lane], acc);
    out[(size_t)b * 64 + lane] = acc;
}

extern "C" void kernel_launch(void* const* d_in, const int* in_sizes, int n_in,
                              void* d_out, int out_size, void* d_ws, size_t ws_size,
                              hipStream_t stream) {
    const int*   seq     = (const int*)  d_in[0];
    const float* embed_W = (const float*)d_in[1];
    const float* ff_w1   = (const float*)d_in[2];
    const float* ff_b1   = (const float*)d_in[3];
    const float* ff_w2   = (const float*)d_in[4];
    const float* ff_b2   = (const float*)d_in[5];
    const float* ln_g    = (const float*)d_in[6];
    const float* ln_b    = (const float*)d_in[7];
    const float* gate_w1 = (const float*)d_in[8];
    const float* gate_b1 = (const float*)d_in[9];
    const float* gate_w2 = (const float*)d_in[10];
    const float* gate_b2 = (const float*)d_in[11];
    const float* read_w  = (const float*)d_in[12];
    const float* read_b  = (const float*)d_in[13];
    const float* out_w   = (const float*)d_in[14];
    const float* out_b   = (const float*)d_in[15];
    float* ws  = (float*)d_ws;
    float* out = (float*)d_out;

    hipLaunchKernelGGL(prep1_kernel, dim3(129), dim3(128), 0, stream,
                       embed_W, ff_w1, ff_b1, ff_w2, ff_b2, ln_g, ln_b,
                       gate_w1, gate_b1, gate_w2, gate_b2, read_w, read_b,
                       out_w, out_b, ws);
    hipLaunchKernelGGL(prep2_kernel, dim3(32), dim3(256), 0, stream, ws);
    hipLaunchKernelGGL(scan_kernel, dim3(Bsz / SW), dim3(SW * 64), 0, stream,
                       seq, ws, out);
}